// Round 4
// baseline (44.761 us; speedup 1.0000x reference)
//
#include <hip/hip_runtime.h>
#include <cstdint>

#define NRC 4          // real channels
#define NCC 6          // complex channels
#define HD 64
#define CW 16          // z/out row width (floats)

typedef _Float16 half8 __attribute__((ext_vector_type(8)));
typedef float f32x4 __attribute__((ext_vector_type(4)));

__device__ __forceinline__ uint32_t pkh(float a, float b) {
    auto h = __builtin_amdgcn_cvt_pkrtz(a, b);   // __fp16 ext_vector(2), 4 bytes
    return __builtin_bit_cast(uint32_t, h);
}

// LDS word map (uint32 units), 12288 words = 49152 B -> 3 blocks/CU, 24 waves/CU:
//   [0,    4096) : W^T f16 both layers, layer l at l*2048: 64 rows x 32 words, rotated 16B blocks
//   [4096, 12288): h tiles, wave wv at 4096 + wv*1024: 32 rows(tokens) x 32 words, rotated
//   route buffer : reuses own wave's h words [hb, hb+64) (dead after final B-reads)
__global__ __launch_bounds__(512, 6) void koop_kernel(
    const float* __restrict__ z,
    const float* __restrict__ W0_r, const float* __restrict__ b0_r,
    const float* __restrict__ Wm_r, const float* __restrict__ bm_r,
    const float* __restrict__ Wl_r, const float* __restrict__ bl_r,
    const float* __restrict__ W0_c, const float* __restrict__ b0_c,
    const float* __restrict__ Wm_c, const float* __restrict__ bm_c,
    const float* __restrict__ Wl_c, const float* __restrict__ bl_c,
    float* __restrict__ out)
{
    __shared__ uint32_t smem[12288];

    const int tid  = threadIdx.x;
    const int lane = tid & 63;
    const int wv   = tid >> 6;        // 0..7
    const int bid  = blockIdx.x;
    const int ch   = bid >> 8;        // consecutive blocks share a channel (L2 weight locality)
    const int tile = bid & 255;
    const int t0   = tile * 256;

    const bool isReal = (ch < NRC);
    const int  pc     = ch - NRC;
    const int  No     = isReal ? 1 : 2;

    const float* W0 = isReal ? (W0_r + ch * HD) : (W0_c + pc * HD);
    const float* b0 = isReal ? (b0_r + ch * HD) : (b0_c + pc * HD);
    const float* Wl = isReal ? (Wl_r + ch * HD) : (Wl_c + pc * HD * 2);
    const float* bl = isReal ? (bl_r + ch)      : (bl_c + pc * 2);

    const int l15  = lane & 15;
    const int g    = lane >> 4;       // 0..3
    const int tokl = lane & 31;       // local token 0..31 (two lanes per token)
    const int hf   = lane >> 5;       // 0/1

    // ---------------- early: per-token z load (overlaps weight staging) ----------------
    const int t = t0 + wv * 32 + tokl;
    float xin = 0.f, z1 = 0.f, z2 = 0.f, sval;
    if (isReal) {
        xin = z[t * CW + ch];
        sval = xin;
    } else {
        float2 zz = *(const float2*)(z + t * CW + NRC + 2 * pc);
        z1 = zz.x; z2 = zz.y;
        sval = z1 * z1 + z2 * z2;
    }

    // ---------------- early: final-layer A fragments from global ----------------
    half8 Af[2];
    #pragma unroll
    for (int kt = 0; kt < 2; ++kt) {
        half8 a;
        #pragma unroll
        for (int e = 0; e < 8; ++e) {
            const int k = kt * 32 + g * 8 + e;
            float w = (l15 < No) ? Wl[k * No + l15] : 0.f;
            a[e] = (_Float16)w;
        }
        Af[kt] = a;
    }

    // ---------------- stage W^T (f16) both layers: one uint4 per thread per layer ----------------
    {
        const int nH  = tid & 63;
        const int blk = tid >> 6;                      // 0..7 (one k-block per thread)
        #pragma unroll
        for (int l = 0; l < 2; ++l) {
            const float* Wm = isReal ? (Wm_r + (l * NRC + ch) * HD * HD)
                                     : (Wm_c + (l * NCC + pc) * HD * HD);
            const float* src = Wm + blk * 8 * HD + nH; // W[k][nH], stride HD per k
            float v0 = src[0],    v1 = src[HD],   v2 = src[2*HD], v3 = src[3*HD];
            float v4 = src[4*HD], v5 = src[5*HD], v6 = src[6*HD], v7 = src[7*HD];
            const int woff = l * 2048 + nH * 32 + (((blk + nH) & 7) << 2);
            uint4 q = { pkh(v0, v1), pkh(v2, v3), pkh(v4, v5), pkh(v6, v7) };
            *(uint4*)&smem[woff] = q;
        }
    }
    __syncthreads();   // the only block-wide barrier

    // ---------------- stage 1: h0 = relu(s*W0 + b0); all 64 lanes, 4 k-blocks each ----------------
    const int hb = 4096 + wv * 1024;
    #pragma unroll
    for (int j = 0; j < 4; ++j) {
        const int blk = hf * 4 + j;
        const int n = blk * 8;
        float a0 = fmaxf(fmaf(sval, W0[n+0], b0[n+0]), 0.f);
        float a1 = fmaxf(fmaf(sval, W0[n+1], b0[n+1]), 0.f);
        float a2 = fmaxf(fmaf(sval, W0[n+2], b0[n+2]), 0.f);
        float a3 = fmaxf(fmaf(sval, W0[n+3], b0[n+3]), 0.f);
        float a4 = fmaxf(fmaf(sval, W0[n+4], b0[n+4]), 0.f);
        float a5 = fmaxf(fmaf(sval, W0[n+5], b0[n+5]), 0.f);
        float a6 = fmaxf(fmaf(sval, W0[n+6], b0[n+6]), 0.f);
        float a7 = fmaxf(fmaf(sval, W0[n+7], b0[n+7]), 0.f);
        const int woff = hb + tokl * 32 + (((blk + tokl) & 7) << 2);
        uint4 q = { pkh(a0, a1), pkh(a2, a3), pkh(a4, a5), pkh(a6, a7) };
        *(uint4*)&smem[woff] = q;
    }

    // ---------------- two hidden layers via MFMA ----------------
    // D[nH][tok]; D col = token (lane&15), D row = nH = 16*m + 4*g + reg.
    // 32 tokens/wave -> acc[4][2] (32 regs), bias folded into C-init.
    for (int l = 0; l < 2; ++l) {
        const float* bm = isReal ? (bm_r + (l * NRC + ch) * HD)
                                 : (bm_c + (l * NCC + pc) * HD);
        f32x4 acc[4][2];
        #pragma unroll
        for (int m = 0; m < 4; ++m) {
            f32x4 bv = *(const f32x4*)(bm + m * 16 + g * 4);
            acc[m][0] = bv;
            acc[m][1] = bv;
        }

        #pragma unroll
        for (int kt = 0; kt < 2; ++kt) {
            half8 A[4];
            #pragma unroll
            for (int m = 0; m < 4; ++m) {
                const int row = m * 16 + l15;
                const int blk = kt * 4 + g;
                A[m] = *(const half8*)&smem[l * 2048 + row * 32 + (((blk + row) & 7) << 2)];
            }
            #pragma unroll
            for (int tt = 0; tt < 2; ++tt) {
                const int row = tt * 16 + l15;
                const int blk = kt * 4 + g;
                half8 Bf = *(const half8*)&smem[hb + row * 32 + (((blk + row) & 7) << 2)];
                #pragma unroll
                for (int m = 0; m < 4; ++m)
                    acc[m][tt] = __builtin_amdgcn_mfma_f32_16x16x32_f16(A[m], Bf, acc[m][tt], 0, 0, 0);
            }
        }

        // epilogue: relu + pack f16 + write back (all reads of this layer precede these writes)
        #pragma unroll
        for (int tt = 0; tt < 2; ++tt) {
            const int row = tt * 16 + l15;
            #pragma unroll
            for (int m = 0; m < 4; ++m) {
                f32x4 v = acc[m][tt];
                float a0 = fmaxf(v[0], 0.f);
                float a1 = fmaxf(v[1], 0.f);
                float a2 = fmaxf(v[2], 0.f);
                float a3 = fmaxf(v[3], 0.f);
                const int blk  = 2 * m + (g >> 1);
                const int woff = hb + row * 32 + (((blk + row) & 7) << 2) + (g & 1) * 2;
                uint2 q = { pkh(a0, a1), pkh(a2, a3) };
                *(uint2*)&smem[woff] = q;
            }
        }
    }

    // ---------------- final layer: out_raw[o][tok] via MFMA (bias in C-init) ----------------
    f32x4 cf0 = (f32x4){0.f, 0.f, 0.f, 0.f};
    if (g == 0) { cf0[0] = bl[0]; if (!isReal) cf0[1] = bl[1]; }
    f32x4 accf[2] = { cf0, cf0 };
    #pragma unroll
    for (int kt = 0; kt < 2; ++kt) {
        #pragma unroll
        for (int tt = 0; tt < 2; ++tt) {
            const int row = tt * 16 + l15;
            const int blk = kt * 4 + g;
            half8 Bf = *(const half8*)&smem[hb + row * 32 + (((blk + row) & 7) << 2)];
            accf[tt] = __builtin_amdgcn_mfma_f32_16x16x32_f16(Af[kt], Bf, accf[tt], 0, 0, 0);
        }
    }

    // ---------------- route results to lane = token (wave-local, reuse own h words) ----------------
    float* smf = (float*)smem;
    const int obase = hb;             // words [hb, hb+64): 32 tok x 2 f32
    if (g == 0) {
        #pragma unroll
        for (int tt = 0; tt < 2; ++tt) {
            const int tok = tt * 16 + l15;
            if (isReal) {
                smf[obase + tok * 2] = accf[tt][0];
            } else {
                float2 mo = { accf[tt][0], accf[tt][1] };
                *(float2*)&smf[obase + tok * 2] = mo;
            }
        }
    }
    __asm__ volatile("s_waitcnt lgkmcnt(0)" ::: "memory");
    __builtin_amdgcn_sched_barrier(0);

    if (hf == 0) {                    // lanes 0..31: one token each
        if (isReal) {
            float lam = smf[obase + tokl * 2];
            out[t * CW + ch] = xin * lam;
        } else {
            float2 mo = *(const float2*)&smf[obase + tokl * 2];
            float ex = __expf(mo.x);
            float mc = ex * __cosf(mo.y);
            float ms = ex * __sinf(mo.y);
            float o1 =  z1 * mc + z2 * ms;
            float o2 =  z2 * mc - z1 * ms;
            *(float2*)(out + t * CW + NRC + 2 * pc) = make_float2(o1, o2);
        }
    }
}

extern "C" void kernel_launch(void* const* d_in, const int* in_sizes, int n_in,
                              void* d_out, int out_size, void* d_ws, size_t ws_size,
                              hipStream_t stream) {
    (void)in_sizes; (void)n_in; (void)d_ws; (void)ws_size; (void)out_size;
    const float* z    = (const float*)d_in[0];
    const float* W0_r = (const float*)d_in[1];
    const float* b0_r = (const float*)d_in[2];
    const float* Wm_r = (const float*)d_in[3];
    const float* bm_r = (const float*)d_in[4];
    const float* Wl_r = (const float*)d_in[5];
    const float* bl_r = (const float*)d_in[6];
    const float* W0_c = (const float*)d_in[7];
    const float* b0_c = (const float*)d_in[8];
    const float* Wm_c = (const float*)d_in[9];
    const float* bm_c = (const float*)d_in[10];
    const float* Wl_c = (const float*)d_in[11];
    const float* bl_c = (const float*)d_in[12];
    float* outp = (float*)d_out;

    dim3 grid(2560), block(512);
    koop_kernel<<<grid, block, 0, stream>>>(z, W0_r, b0_r, Wm_r, bm_r, Wl_r, bl_r,
                                            W0_c, b0_c, Wm_c, bm_c, Wl_c, bl_c, outp);
}